// Round 1
// baseline (655.429 us; speedup 1.0000x reference)
//
#include <hip/hip_runtime.h>

// LocalFeatureAggregation — round 4: occupancy + VALU diet.
//  * feaA shrunk to a single-point buffer: LDS 60416 -> 43008 B => 3 blocks/CU
//    (__launch_bounds__(256,3)), 12 waves/CU instead of 8.
//  * f2bf/pack2 now use compiler __bf16 casts (v_cvt_pk_bf16_f32) instead of
//    5-7 op manual RNE bit-twiddling.
//  * log2e folded into W_attn frags at prep => softmax uses v_exp_f32 directly.
//  * Both points' gather + raw loads hoisted to iteration head for latency overlap.
// Requires ws_size >= 86784 bytes (prep kernel stages frag tables into d_ws).

#define KNB   16
#define CR    10
#define CIN   64
#define CCAT  128
#define COUT  128
#define NPTS  131072
#define EPS   1e-5f
#define LOG2E 1.4426950408889634f

// d_ws layout (bytes)
#define WS_WB   0        // W_attn B-frags (pre-scaled by log2e): 2048 * 16 B = 32768
#define WS_W3   32768    // [W_out;W_sc] BN-folded B-frags: 3072 * 16 B = 49152
#define WS_WNB  81920    // W_nb BN-folded B-frags (K padded to 32): 256 * 16 B = 4096
#define WS_B3   86016    // bias3[128] fp32
#define WS_BNB  86528    // binb[64] fp32   -> total 86784

typedef const float* fp;
typedef short bf16x8 __attribute__((ext_vector_type(8)));
typedef float f32x4  __attribute__((ext_vector_type(4)));
typedef __bf16 bf16x2 __attribute__((ext_vector_type(2)));

__device__ __forceinline__ unsigned short f2bf(float x) {
    return __builtin_bit_cast(unsigned short, (__bf16)x);     // HW RNE cvt
}
__device__ __forceinline__ unsigned int pack2(float a, float b) {
    bf16x2 v; v.x = (__bf16)a; v.y = (__bf16)b;               // fuses to v_cvt_pk_bf16_f32
    return __builtin_bit_cast(unsigned int, v);
}
__device__ __forceinline__ float bf2f(unsigned short h) {
    return __uint_as_float(((unsigned int)h) << 16);
}
__device__ __forceinline__ float lrelu(float x) { return fmaxf(x, 0.2f * x); }

// ---------------------------------------------------------------------------
// Prep: build all weight-fragment tables in d_ws (runs every launch; d_ws is
// re-poisoned by the harness before each timed call).
// ---------------------------------------------------------------------------
__global__ __launch_bounds__(256) void lfa_prep(
    fp W_nb, fp b_nb, fp g_nb, fp be_nb, fp m_nb, fp v_nb,
    fp W_attn,
    fp W_out, fp b_out, fp g_out, fp be_out, fp m_out, fp v_out,
    fp W_sc,  fp b_sc,  fp g_sc,  fp be_sc,  fp m_sc,  fp v_sc,
    unsigned char* __restrict__ ws)
{
    const int t = blockIdx.x * 256 + threadIdx.x;
    if (t < 2048) {                                   // W_attn frags (x log2e)
        const int n0 = t >> 8, s = (t >> 6) & 3, ln = t & 63;
        const int n = (n0 << 4) + (ln & 15);
        unsigned int v[4];
        #pragma unroll
        for (int jj = 0; jj < 4; ++jj) {
            const int k = (s << 5) + ((ln >> 4) << 3) + jj * 2;
            v[jj] = pack2(W_attn[k * CCAT + n] * LOG2E,
                          W_attn[(k + 1) * CCAT + n] * LOG2E);
        }
        *(uint4*)(ws + WS_WB + t * 16) = make_uint4(v[0], v[1], v[2], v[3]);
    } else if (t < 5120) {                            // [W_out;W_sc] BN-folded frags
        const int e = t - 2048;
        const int t8 = e / 384, rem = e % 384, s = rem >> 6, ln = rem & 63;
        const int d = (t8 << 4) + (ln & 15);
        const float so = g_out[d] * rsqrtf(v_out[d] + EPS);
        const float ss = g_sc[d]  * rsqrtf(v_sc[d]  + EPS);
        unsigned int v[4];
        #pragma unroll
        for (int jj = 0; jj < 4; ++jj) {
            float a[2];
            #pragma unroll
            for (int h = 0; h < 2; ++h) {
                const int k = (s << 5) + ((ln >> 4) << 3) + jj * 2 + h;   // 0..191
                a[h] = (k < CCAT) ? W_out[k * COUT + d] * so
                                  : W_sc[(k - CCAT) * COUT + d] * ss;
            }
            v[jj] = pack2(a[0], a[1]);
        }
        *(uint4*)(ws + WS_W3 + e * 16) = make_uint4(v[0], v[1], v[2], v[3]);
    } else if (t < 5376) {                            // W_nb BN-prescaled frags
        const int e = t - 5120;
        const int n0 = e >> 6, ln = e & 63;
        const int n = (n0 << 4) + (ln & 15);
        const float sn = g_nb[n] * rsqrtf(v_nb[n] + EPS);
        unsigned int v[4];
        #pragma unroll
        for (int jj = 0; jj < 4; ++jj) {
            float a[2];
            #pragma unroll
            for (int h = 0; h < 2; ++h) {
                const int k = ((ln >> 4) << 3) + jj * 2 + h;
                a[h] = (k < CR) ? W_nb[k * 64 + n] * sn : 0.f;
            }
            v[jj] = pack2(a[0], a[1]);
        }
        *(uint4*)(ws + WS_WNB + e * 16) = make_uint4(v[0], v[1], v[2], v[3]);
    } else if (t < 5504) {                            // bias3
        const int d = t - 5376;
        const float so = g_out[d] * rsqrtf(v_out[d] + EPS);
        const float ss = g_sc[d]  * rsqrtf(v_sc[d]  + EPS);
        ((float*)(ws + WS_B3))[d] =
              (b_out[d] - m_out[d]) * so + be_out[d]
            + (b_sc[d]  - m_sc[d])  * ss + be_sc[d];
    } else if (t < 5568) {                            // nb bias
        const int d = t - 5504;
        const float sn = g_nb[d] * rsqrtf(v_nb[d] + EPS);
        ((float*)(ws + WS_BNB))[d] = (b_nb[d] - m_nb[d]) * sn + be_nb[d];
    }
}

// ---------------------------------------------------------------------------
// Main: 2048 blocks x 256 thr (4 waves). Each wave owns 16 consecutive points:
// 8 iters x 2 points (gather + nb-MLP MFMA + attn MFMA + softmax/pool into a
// per-wave LDS slab), then one fused M=16,K=192 MFMA GEMM epilogue. No barriers.
// LDS = 43008 B/block -> 3 blocks/CU.
// ---------------------------------------------------------------------------
__global__ __launch_bounds__(256, 3) void lfa_main(
    fp feature, fp raw, const int* __restrict__ nidx,
    const unsigned char* __restrict__ ws, float* __restrict__ out)
{
    __shared__ __align__(16) unsigned short feaA[4][16][136];       // 17408 B (single-pt)
    __shared__ __align__(16) unsigned short pooledA[4][16][200];    // 25600 B ([pooled|feat])

    const int tid  = threadIdx.x;
    const int w    = tid >> 6;
    const int lane = tid & 63;
    const int quad = lane >> 4;
    const int l15  = lane & 15;
    const int p0   = (blockIdx.x * 4 + w) * 16;    // wave's 16 points
    const int b    = p0 >> 16;                     // batch (16-pt range never straddles)

    // ---- invariant B-frags: W_attn (compiler chooses residency vs remat) ----
    bf16x8 WB[8][4];
    #pragma unroll
    for (int n0 = 0; n0 < 8; ++n0)
        #pragma unroll
        for (int s = 0; s < 4; ++s)
            WB[n0][s] = *(const bf16x8*)(ws + WS_WB + (((n0 * 4 + s) * 64 + lane) << 4));

    float binb[4];
    #pragma unroll
    for (int j = 0; j < 4; ++j)
        binb[j] = ((const float*)(ws + WS_BNB))[j * 16 + l15];

    #pragma unroll 1
    for (int it = 0; it < 8; ++it) {
        const int pp0 = p0 + it * 2;

        // neighbor indices for both points (lanes 0..31; contiguous layout)
        int idxv = 0;
        if (lane < 32) idxv = nidx[pp0 * KNB + lane];

        // stage both center-feature rows into pooledA cols 128..191 (bf16)
        if (lane < 32) {
            const int pt = lane >> 4, c4 = l15 * 4;
            const float4 cf = *(const float4*)&feature[(size_t)(pp0 + pt) * CIN + c4];
            uint2 pk; pk.x = pack2(cf.x, cf.y); pk.y = pack2(cf.z, cf.w);
            *(uint2*)&pooledA[w][it * 2 + pt][CCAT + c4] = pk;
        }

        // ---- hoisted gather loads for BOTH points (longest-latency ops) ----
        float4 gv[2][4];
        #pragma unroll
        for (int pt = 0; pt < 2; ++pt)
            #pragma unroll
            for (int i = 0; i < 4; ++i) {
                const int ni = __shfl(idxv, pt * 16 + i * 4 + quad, 64);
                gv[pt][i] = *(const float4*)&feature[(size_t)((b << 16) + ni) * CIN + l15 * 4];
            }

        // ---- hoisted raw loads + bf16 pack for BOTH points (K padded 10->32) ----
        bf16x8 anb[2];
        #pragma unroll
        for (int pt = 0; pt < 2; ++pt) {
            bf16x8 a = {0, 0, 0, 0, 0, 0, 0, 0};
            const float* rp = raw + (size_t)(pp0 + pt) * (KNB * CR) + l15 * CR;
            if (quad == 0) {
                const float2 r0 = *(const float2*)(rp + 0);
                const float2 r1 = *(const float2*)(rp + 2);
                const float2 r2 = *(const float2*)(rp + 4);
                const float2 r3 = *(const float2*)(rp + 6);
                a[0] = (short)f2bf(r0.x); a[1] = (short)f2bf(r0.y);
                a[2] = (short)f2bf(r1.x); a[3] = (short)f2bf(r1.y);
                a[4] = (short)f2bf(r2.x); a[5] = (short)f2bf(r2.y);
                a[6] = (short)f2bf(r3.x); a[7] = (short)f2bf(r3.y);
            } else if (quad == 1) {
                const float2 r4 = *(const float2*)(rp + 8);
                a[0] = (short)f2bf(r4.x); a[1] = (short)f2bf(r4.y);
            }
            anb[pt] = a;
        }

        #pragma unroll
        for (int pt = 0; pt < 2; ++pt) {

            // ---- nb-MLP MFMA (W prescaled by BN); keep outputs for pool ----
            float nbC[4][4];
            #pragma unroll
            for (int n0 = 0; n0 < 4; ++n0) {
                const bf16x8 bw = *(const bf16x8*)(ws + WS_WNB + ((n0 * 64 + lane) << 4));
                f32x4 c = {0.f, 0.f, 0.f, 0.f};
                c = __builtin_amdgcn_mfma_f32_16x16x32_bf16(anb[pt], bw, c, 0, 0, 0);
                #pragma unroll
                for (int r = 0; r < 4; ++r) {
                    const float x = lrelu(c[r] + binb[n0]);
                    nbC[n0][r] = x;
                    feaA[w][quad * 4 + r][64 + n0 * 16 + l15] = f2bf(x);
                }
            }

            // ---- gather writes (A-layout rows, b64) ----
            #pragma unroll
            for (int i = 0; i < 4; ++i) {
                uint2 pk; pk.x = pack2(gv[pt][i].x, gv[pt][i].y);
                pk.y = pack2(gv[pt][i].z, gv[pt][i].w);
                *(uint2*)&feaA[w][i * 4 + quad][l15 * 4] = pk;
            }

            // ---- attn A-frags ----
            bf16x8 A[4];
            #pragma unroll
            for (int s = 0; s < 4; ++s)
                A[s] = *(const bf16x8*)&feaA[w][l15][s * 32 + quad * 8];

            // ---- 8 d-tiles: MFMA -> softmax over k (logits pre-scaled by log2e,
            //      so exp == v_exp_f32 directly; no max-sub) -> pool ----
            #pragma unroll
            for (int n0 = 0; n0 < 8; ++n0) {
                f32x4 c = {0.f, 0.f, 0.f, 0.f};
                #pragma unroll
                for (int s = 0; s < 4; ++s)
                    c = __builtin_amdgcn_mfma_f32_16x16x32_bf16(A[s], WB[n0][s], c, 0, 0, 0);
                const float e0 = __builtin_amdgcn_exp2f(c[0]);
                const float e1 = __builtin_amdgcn_exp2f(c[1]);
                const float e2 = __builtin_amdgcn_exp2f(c[2]);
                const float e3 = __builtin_amdgcn_exp2f(c[3]);
                float den = e0 + e1 + e2 + e3;
                float num;
                if (n0 < 4) {
                    num = e0 * bf2f(feaA[w][quad * 4 + 0][n0 * 16 + l15])
                        + e1 * bf2f(feaA[w][quad * 4 + 1][n0 * 16 + l15])
                        + e2 * bf2f(feaA[w][quad * 4 + 2][n0 * 16 + l15])
                        + e3 * bf2f(feaA[w][quad * 4 + 3][n0 * 16 + l15]);
                } else {
                    num = e0 * nbC[n0 - 4][0] + e1 * nbC[n0 - 4][1]
                        + e2 * nbC[n0 - 4][2] + e3 * nbC[n0 - 4][3];
                }
                num += __shfl_xor(num, 16, 64);
                den += __shfl_xor(den, 16, 64);
                num += __shfl_xor(num, 32, 64);
                den += __shfl_xor(den, 32, 64);
                const float pp = __fdividef(num, den);
                if (quad == 0)
                    pooledA[w][it * 2 + pt][n0 * 16 + l15] = f2bf(pp);
            }
        }
    }

    // ---- fused phase 3: out = lrelu([pooled|feat] @ W3hat + bias3), M=16 ----
    bf16x8 A3[6];
    #pragma unroll
    for (int s = 0; s < 6; ++s)
        A3[s] = *(const bf16x8*)&pooledA[w][l15][s * 32 + quad * 8];
    #pragma unroll
    for (int t = 0; t < 8; ++t) {
        f32x4 c = {0.f, 0.f, 0.f, 0.f};
        #pragma unroll
        for (int s = 0; s < 6; ++s) {
            const bf16x8 bw = *(const bf16x8*)(ws + WS_W3 + (((t * 6 + s) * 64 + lane) << 4));
            c = __builtin_amdgcn_mfma_f32_16x16x32_bf16(A3[s], bw, c, 0, 0, 0);
        }
        const float bz = ((const float*)(ws + WS_B3))[t * 16 + l15];
        #pragma unroll
        for (int r = 0; r < 4; ++r)
            out[(size_t)(p0 + quad * 4 + r) * COUT + t * 16 + l15] = lrelu(c[r] + bz);
    }
}

extern "C" void kernel_launch(void* const* d_in, const int* in_sizes, int n_in,
                              void* d_out, int out_size, void* d_ws, size_t ws_size,
                              hipStream_t stream)
{
    fp feature = (fp)d_in[1];
    fp raw     = (fp)d_in[2];
    const int* nidx = (const int*)d_in[3];
    fp W_nb = (fp)d_in[4],  b_nb = (fp)d_in[5],  g_nb = (fp)d_in[6];
    fp be_nb = (fp)d_in[7], m_nb = (fp)d_in[8],  v_nb = (fp)d_in[9];
    fp W_attn = (fp)d_in[10];
    fp W_out = (fp)d_in[11], b_out = (fp)d_in[12], g_out = (fp)d_in[13];
    fp be_out = (fp)d_in[14], m_out = (fp)d_in[15], v_out = (fp)d_in[16];
    fp W_sc = (fp)d_in[17], b_sc = (fp)d_in[18], g_sc = (fp)d_in[19];
    fp be_sc = (fp)d_in[20], m_sc = (fp)d_in[21], v_sc = (fp)d_in[22];

    hipLaunchKernelGGL(lfa_prep, dim3(22), dim3(256), 0, stream,
                       W_nb, b_nb, g_nb, be_nb, m_nb, v_nb,
                       W_attn,
                       W_out, b_out, g_out, be_out, m_out, v_out,
                       W_sc, b_sc, g_sc, be_sc, m_sc, v_sc,
                       (unsigned char*)d_ws);
    hipLaunchKernelGGL(lfa_main, dim3(2048), dim3(256), 0, stream,
                       feature, raw, nidx,
                       (const unsigned char*)d_ws, (float*)d_out);
}

// Round 2
// 418.941 us; speedup vs baseline: 1.5645x; 1.5645x over previous
//
#include <hip/hip_runtime.h>

// LocalFeatureAggregation — round 5: recover from round-4 spill regression.
//  * Round-3 structure restored (per-pt gather issue, launch_bounds(256,2) so
//    the allocator reproduces the 124-VGPR no-spill allocation).
//  * KEEP: single-point feaA (LDS 43008 B -> 3 blocks/CU, LDS-capped; verified
//    correct in round 4), __bf16 HW casts, log2e-folded W_attn + v_exp_f32.
//  * REVERT: both-points gather/raw hoist (spill trigger: VGPR 124->84,
//    FETCH 274MB->1.18GB of scratch fill).
// Requires ws_size >= 86784 bytes (prep kernel stages frag tables into d_ws).

#define KNB   16
#define CR    10
#define CIN   64
#define CCAT  128
#define COUT  128
#define NPTS  131072
#define EPS   1e-5f
#define LOG2E 1.4426950408889634f

// d_ws layout (bytes)
#define WS_WB   0        // W_attn B-frags (pre-scaled by log2e): 2048 * 16 B = 32768
#define WS_W3   32768    // [W_out;W_sc] BN-folded B-frags: 3072 * 16 B = 49152
#define WS_WNB  81920    // W_nb BN-folded B-frags (K padded to 32): 256 * 16 B = 4096
#define WS_B3   86016    // bias3[128] fp32
#define WS_BNB  86528    // binb[64] fp32   -> total 86784

typedef const float* fp;
typedef short bf16x8 __attribute__((ext_vector_type(8)));
typedef float f32x4  __attribute__((ext_vector_type(4)));
typedef __bf16 bf16x2 __attribute__((ext_vector_type(2)));

__device__ __forceinline__ unsigned short f2bf(float x) {
    return __builtin_bit_cast(unsigned short, (__bf16)x);     // HW RNE cvt
}
__device__ __forceinline__ unsigned int pack2(float a, float b) {
    bf16x2 v; v.x = (__bf16)a; v.y = (__bf16)b;               // v_cvt_pk_bf16_f32
    return __builtin_bit_cast(unsigned int, v);
}
__device__ __forceinline__ float bf2f(unsigned short h) {
    return __uint_as_float(((unsigned int)h) << 16);
}
__device__ __forceinline__ float lrelu(float x) { return fmaxf(x, 0.2f * x); }

// ---------------------------------------------------------------------------
// Prep: build all weight-fragment tables in d_ws (runs every launch; d_ws is
// re-poisoned by the harness before each timed call).
// ---------------------------------------------------------------------------
__global__ __launch_bounds__(256) void lfa_prep(
    fp W_nb, fp b_nb, fp g_nb, fp be_nb, fp m_nb, fp v_nb,
    fp W_attn,
    fp W_out, fp b_out, fp g_out, fp be_out, fp m_out, fp v_out,
    fp W_sc,  fp b_sc,  fp g_sc,  fp be_sc,  fp m_sc,  fp v_sc,
    unsigned char* __restrict__ ws)
{
    const int t = blockIdx.x * 256 + threadIdx.x;
    if (t < 2048) {                                   // W_attn frags (x log2e)
        const int n0 = t >> 8, s = (t >> 6) & 3, ln = t & 63;
        const int n = (n0 << 4) + (ln & 15);
        unsigned int v[4];
        #pragma unroll
        for (int jj = 0; jj < 4; ++jj) {
            const int k = (s << 5) + ((ln >> 4) << 3) + jj * 2;
            v[jj] = pack2(W_attn[k * CCAT + n] * LOG2E,
                          W_attn[(k + 1) * CCAT + n] * LOG2E);
        }
        *(uint4*)(ws + WS_WB + t * 16) = make_uint4(v[0], v[1], v[2], v[3]);
    } else if (t < 5120) {                            // [W_out;W_sc] BN-folded frags
        const int e = t - 2048;
        const int t8 = e / 384, rem = e % 384, s = rem >> 6, ln = rem & 63;
        const int d = (t8 << 4) + (ln & 15);
        const float so = g_out[d] * rsqrtf(v_out[d] + EPS);
        const float ss = g_sc[d]  * rsqrtf(v_sc[d]  + EPS);
        unsigned int v[4];
        #pragma unroll
        for (int jj = 0; jj < 4; ++jj) {
            float a[2];
            #pragma unroll
            for (int h = 0; h < 2; ++h) {
                const int k = (s << 5) + ((ln >> 4) << 3) + jj * 2 + h;   // 0..191
                a[h] = (k < CCAT) ? W_out[k * COUT + d] * so
                                  : W_sc[(k - CCAT) * COUT + d] * ss;
            }
            v[jj] = pack2(a[0], a[1]);
        }
        *(uint4*)(ws + WS_W3 + e * 16) = make_uint4(v[0], v[1], v[2], v[3]);
    } else if (t < 5376) {                            // W_nb BN-prescaled frags
        const int e = t - 5120;
        const int n0 = e >> 6, ln = e & 63;
        const int n = (n0 << 4) + (ln & 15);
        const float sn = g_nb[n] * rsqrtf(v_nb[n] + EPS);
        unsigned int v[4];
        #pragma unroll
        for (int jj = 0; jj < 4; ++jj) {
            float a[2];
            #pragma unroll
            for (int h = 0; h < 2; ++h) {
                const int k = ((ln >> 4) << 3) + jj * 2 + h;
                a[h] = (k < CR) ? W_nb[k * 64 + n] * sn : 0.f;
            }
            v[jj] = pack2(a[0], a[1]);
        }
        *(uint4*)(ws + WS_WNB + e * 16) = make_uint4(v[0], v[1], v[2], v[3]);
    } else if (t < 5504) {                            // bias3
        const int d = t - 5376;
        const float so = g_out[d] * rsqrtf(v_out[d] + EPS);
        const float ss = g_sc[d]  * rsqrtf(v_sc[d]  + EPS);
        ((float*)(ws + WS_B3))[d] =
              (b_out[d] - m_out[d]) * so + be_out[d]
            + (b_sc[d]  - m_sc[d])  * ss + be_sc[d];
    } else if (t < 5568) {                            // nb bias
        const int d = t - 5504;
        const float sn = g_nb[d] * rsqrtf(v_nb[d] + EPS);
        ((float*)(ws + WS_BNB))[d] = (b_nb[d] - m_nb[d]) * sn + be_nb[d];
    }
}

// ---------------------------------------------------------------------------
// Main: 2048 blocks x 256 thr (4 waves). Each wave owns 16 consecutive points:
// 8 iters x 2 points (gather + nb-MLP MFMA + attn MFMA + softmax/pool into a
// per-wave LDS slab), then one fused M=16,K=192 MFMA GEMM epilogue. No barriers.
// LDS = 43008 B/block -> 3 blocks/CU (LDS-capped; VGPR ~124 allows 4 waves/SIMD).
// ---------------------------------------------------------------------------
__global__ __launch_bounds__(256, 2) void lfa_main(
    fp feature, fp raw, const int* __restrict__ nidx,
    const unsigned char* __restrict__ ws, float* __restrict__ out)
{
    __shared__ __align__(16) unsigned short feaA[4][16][136];       // 17408 B (single-pt)
    __shared__ __align__(16) unsigned short pooledA[4][16][200];    // 25600 B ([pooled|feat])

    const int tid  = threadIdx.x;
    const int w    = tid >> 6;
    const int lane = tid & 63;
    const int quad = lane >> 4;
    const int l15  = lane & 15;
    const int p0   = (blockIdx.x * 4 + w) * 16;    // wave's 16 points
    const int b    = p0 >> 16;                     // batch (16-pt range never straddles)

    // ---- invariant B-frags: W_attn in registers (128 VGPRs) ----
    bf16x8 WB[8][4];
    #pragma unroll
    for (int n0 = 0; n0 < 8; ++n0)
        #pragma unroll
        for (int s = 0; s < 4; ++s)
            WB[n0][s] = *(const bf16x8*)(ws + WS_WB + (((n0 * 4 + s) * 64 + lane) << 4));

    float binb[4];
    #pragma unroll
    for (int j = 0; j < 4; ++j)
        binb[j] = ((const float*)(ws + WS_BNB))[j * 16 + l15];

    #pragma unroll 1
    for (int it = 0; it < 8; ++it) {
        const int pp0 = p0 + it * 2;

        // neighbor indices for both points (lanes 0..31; contiguous layout)
        int idxv = 0;
        if (lane < 32) idxv = nidx[pp0 * KNB + lane];

        // stage both center-feature rows into pooledA cols 128..191 (bf16)
        if (lane < 32) {
            const int pt = lane >> 4, c4 = l15 * 4;
            const float4 cf = *(const float4*)&feature[(size_t)(pp0 + pt) * CIN + c4];
            uint2 pk; pk.x = pack2(cf.x, cf.y); pk.y = pack2(cf.z, cf.w);
            *(uint2*)&pooledA[w][it * 2 + pt][CCAT + c4] = pk;
        }

        #pragma unroll
        for (int pt = 0; pt < 2; ++pt) {
            const int p = pp0 + pt;

            // ---- gather loads (issued early, consumed after nb-MLP) ----
            float4 gv[4];
            #pragma unroll
            for (int i = 0; i < 4; ++i) {
                const int ni = __shfl(idxv, pt * 16 + i * 4 + quad, 64);
                gv[i] = *(const float4*)&feature[(size_t)((b << 16) + ni) * CIN + l15 * 4];
            }

            // ---- nb-MLP A-frag directly from raw (K padded 10->32) ----
            bf16x8 anb = {0, 0, 0, 0, 0, 0, 0, 0};
            {
                const float* rp = raw + (size_t)p * (KNB * CR) + l15 * CR;
                if (quad == 0) {
                    const float2 r0 = *(const float2*)(rp + 0);
                    const float2 r1 = *(const float2*)(rp + 2);
                    const float2 r2 = *(const float2*)(rp + 4);
                    const float2 r3 = *(const float2*)(rp + 6);
                    anb[0] = (short)f2bf(r0.x); anb[1] = (short)f2bf(r0.y);
                    anb[2] = (short)f2bf(r1.x); anb[3] = (short)f2bf(r1.y);
                    anb[4] = (short)f2bf(r2.x); anb[5] = (short)f2bf(r2.y);
                    anb[6] = (short)f2bf(r3.x); anb[7] = (short)f2bf(r3.y);
                } else if (quad == 1) {
                    const float2 r4 = *(const float2*)(rp + 8);
                    anb[0] = (short)f2bf(r4.x); anb[1] = (short)f2bf(r4.y);
                }
            }

            // ---- nb-MLP MFMA (W prescaled by BN); keep outputs for pool ----
            float nbC[4][4];
            #pragma unroll
            for (int n0 = 0; n0 < 4; ++n0) {
                const bf16x8 bw = *(const bf16x8*)(ws + WS_WNB + ((n0 * 64 + lane) << 4));
                f32x4 c = {0.f, 0.f, 0.f, 0.f};
                c = __builtin_amdgcn_mfma_f32_16x16x32_bf16(anb, bw, c, 0, 0, 0);
                #pragma unroll
                for (int r = 0; r < 4; ++r) {
                    const float x = lrelu(c[r] + binb[n0]);
                    nbC[n0][r] = x;
                    feaA[w][quad * 4 + r][64 + n0 * 16 + l15] = f2bf(x);
                }
            }

            // ---- gather writes (A-layout rows, b64) ----
            #pragma unroll
            for (int i = 0; i < 4; ++i) {
                uint2 pk; pk.x = pack2(gv[i].x, gv[i].y); pk.y = pack2(gv[i].z, gv[i].w);
                *(uint2*)&feaA[w][i * 4 + quad][l15 * 4] = pk;
            }

            // ---- attn A-frags ----
            bf16x8 A[4];
            #pragma unroll
            for (int s = 0; s < 4; ++s)
                A[s] = *(const bf16x8*)&feaA[w][l15][s * 32 + quad * 8];

            // ---- 8 d-tiles: MFMA -> softmax over k (logits pre-scaled by log2e,
            //      so exp == v_exp_f32 directly; no max-sub) -> pool ----
            #pragma unroll
            for (int n0 = 0; n0 < 8; ++n0) {
                f32x4 c = {0.f, 0.f, 0.f, 0.f};
                #pragma unroll
                for (int s = 0; s < 4; ++s)
                    c = __builtin_amdgcn_mfma_f32_16x16x32_bf16(A[s], WB[n0][s], c, 0, 0, 0);
                const float e0 = __builtin_amdgcn_exp2f(c[0]);
                const float e1 = __builtin_amdgcn_exp2f(c[1]);
                const float e2 = __builtin_amdgcn_exp2f(c[2]);
                const float e3 = __builtin_amdgcn_exp2f(c[3]);
                float den = e0 + e1 + e2 + e3;
                float num;
                if (n0 < 4) {
                    num = e0 * bf2f(feaA[w][quad * 4 + 0][n0 * 16 + l15])
                        + e1 * bf2f(feaA[w][quad * 4 + 1][n0 * 16 + l15])
                        + e2 * bf2f(feaA[w][quad * 4 + 2][n0 * 16 + l15])
                        + e3 * bf2f(feaA[w][quad * 4 + 3][n0 * 16 + l15]);
                } else {
                    num = e0 * nbC[n0 - 4][0] + e1 * nbC[n0 - 4][1]
                        + e2 * nbC[n0 - 4][2] + e3 * nbC[n0 - 4][3];
                }
                num += __shfl_xor(num, 16, 64);
                den += __shfl_xor(den, 16, 64);
                num += __shfl_xor(num, 32, 64);
                den += __shfl_xor(den, 32, 64);
                const float pp = __fdividef(num, den);
                if (quad == 0)
                    pooledA[w][it * 2 + pt][n0 * 16 + l15] = f2bf(pp);
            }
        }
    }

    // ---- fused phase 3: out = lrelu([pooled|feat] @ W3hat + bias3), M=16 ----
    bf16x8 A3[6];
    #pragma unroll
    for (int s = 0; s < 6; ++s)
        A3[s] = *(const bf16x8*)&pooledA[w][l15][s * 32 + quad * 8];
    #pragma unroll
    for (int t = 0; t < 8; ++t) {
        f32x4 c = {0.f, 0.f, 0.f, 0.f};
        #pragma unroll
        for (int s = 0; s < 6; ++s) {
            const bf16x8 bw = *(const bf16x8*)(ws + WS_W3 + (((t * 6 + s) * 64 + lane) << 4));
            c = __builtin_amdgcn_mfma_f32_16x16x32_bf16(A3[s], bw, c, 0, 0, 0);
        }
        const float bz = ((const float*)(ws + WS_B3))[t * 16 + l15];
        #pragma unroll
        for (int r = 0; r < 4; ++r)
            out[(size_t)(p0 + quad * 4 + r) * COUT + t * 16 + l15] = lrelu(c[r] + bz);
    }
}

extern "C" void kernel_launch(void* const* d_in, const int* in_sizes, int n_in,
                              void* d_out, int out_size, void* d_ws, size_t ws_size,
                              hipStream_t stream)
{
    fp feature = (fp)d_in[1];
    fp raw     = (fp)d_in[2];
    const int* nidx = (const int*)d_in[3];
    fp W_nb = (fp)d_in[4],  b_nb = (fp)d_in[5],  g_nb = (fp)d_in[6];
    fp be_nb = (fp)d_in[7], m_nb = (fp)d_in[8],  v_nb = (fp)d_in[9];
    fp W_attn = (fp)d_in[10];
    fp W_out = (fp)d_in[11], b_out = (fp)d_in[12], g_out = (fp)d_in[13];
    fp be_out = (fp)d_in[14], m_out = (fp)d_in[15], v_out = (fp)d_in[16];
    fp W_sc = (fp)d_in[17], b_sc = (fp)d_in[18], g_sc = (fp)d_in[19];
    fp be_sc = (fp)d_in[20], m_sc = (fp)d_in[21], v_sc = (fp)d_in[22];

    hipLaunchKernelGGL(lfa_prep, dim3(22), dim3(256), 0, stream,
                       W_nb, b_nb, g_nb, be_nb, m_nb, v_nb,
                       W_attn,
                       W_out, b_out, g_out, be_out, m_out, v_out,
                       W_sc, b_sc, g_sc, be_sc, m_sc, v_sc,
                       (unsigned char*)d_ws);
    hipLaunchKernelGGL(lfa_main, dim3(2048), dim3(256), 0, stream,
                       feature, raw, nidx,
                       (const unsigned char*)d_ws, (float*)d_out);
}